// Round 9
// baseline (195.743 us; speedup 1.0000x reference)
//
#include <hip/hip_runtime.h>
#include <math.h>

#define EPSD 1e-8
#define EPSF 1e-8f
#define IMG_H 512
#define IMG_W 512
#define TEX_W 1024
#define TEX_H 1024
#define REJ_SLACK 1e-3    // reject if corner-max < -REJ_SLACK (>> f64 rounding)
#define FULL_THR 16.0     // full-cover if corner-min >= FULL_THR (>> rounding)
#define TILE_W 32
#define TILE_H 16
#define TILES_X (IMG_W / TILE_W)            // 16
#define TILES_Y (IMG_H / TILE_H)            // 32
#define TILES_PER_IMG (TILES_X * TILES_Y)   // 512

// ---------------------------------------------------------------------------
// Kernel 1: project vertices in f64 -> vpixd (x_pix, y_pix, z_cam)
// ---------------------------------------------------------------------------
__global__ __launch_bounds__(256) void k_project(
    const float* __restrict__ v,
    const float* __restrict__ campos,
    const float* __restrict__ camrot,
    const float* __restrict__ focal,
    const float* __restrict__ princpt,
    double* __restrict__ vpixd,
    int N, int V) {
#pragma clang fp contract(off)
  int i = blockIdx.x * blockDim.x + threadIdx.x;
  if (i >= N * V) return;
  int n = i / V;
  const float* vv = v + (size_t)i * 3;
  double ax = (double)vv[0] - (double)campos[n * 3 + 0];
  double ay = (double)vv[1] - (double)campos[n * 3 + 1];
  double az = (double)vv[2] - (double)campos[n * 3 + 2];
  const float* R = camrot + (size_t)n * 9;
  double cx = ((double)R[0] * ax + (double)R[1] * ay) + (double)R[2] * az;
  double cy = ((double)R[3] * ax + (double)R[4] * ay) + (double)R[5] * az;
  double cz = ((double)R[6] * ax + (double)R[7] * ay) + (double)R[8] * az;
  double zz = fmax(cz, EPSD);
  double xd = cx / zz;
  double yd = cy / zz;
  const float* Fc = focal + (size_t)n * 4;
  double px = ((double)Fc[0] * xd + (double)Fc[1] * yd) + (double)princpt[n * 2 + 0];
  double py = ((double)Fc[2] * xd + (double)Fc[3] * yd) + (double)princpt[n * 2 + 1];
  vpixd[(size_t)i * 3 + 0] = px;
  vpixd[(size_t)i * 3 + 1] = py;
  vpixd[(size_t)i * 3 + 2] = cz;
}

// ---------------------------------------------------------------------------
// Kernel 2: per-triangle coefficient setup (f64). Also zeroes the steal
// counter (thread 0) -- stream order makes it visible to k_raster.
//   W_k = px*EA_k + py*EB_k + EC_k ; inside <=> all W_k >= 0
//   zi  = px*P + py*S + Q
// Invalid triangles: EA=EB=0, EC=-1 -> never inside, never survives cull.
// Layout per (n,f), 6 x double2:
//  [0]=(EA0,EB0) [1]=(EC0,EA1) [2]=(EB1,EC1) [3]=(EA2,EB2) [4]=(EC2,P) [5]=(Q,S)
// ---------------------------------------------------------------------------
__global__ __launch_bounds__(256) void k_setup(
    const double* __restrict__ vpixd,
    const int* __restrict__ vi,
    double2* __restrict__ tri,
    float4* __restrict__ bbox,
    int* __restrict__ counter,
    int N, int V, int F) {
#pragma clang fp contract(off)
  int i = blockIdx.x * blockDim.x + threadIdx.x;
  if (i == 0) counter[0] = 0;
  if (i >= N * F) return;
  int n = i / F;
  int f = i - n * F;
  int i0 = vi[f * 3 + 0], i1 = vi[f * 3 + 1], i2 = vi[f * 3 + 2];
  const double* p0 = vpixd + ((size_t)n * V + i0) * 3;
  const double* p1 = vpixd + ((size_t)n * V + i1) * 3;
  const double* p2 = vpixd + ((size_t)n * V + i2) * 3;
  double x0 = p0[0], y0 = p0[1], z0 = p0[2];
  double x1 = p1[0], y1 = p1[1], z1 = p1[2];
  double x2 = p2[0], y2 = p2[1], z2 = p2[2];
  double A0 = y2 - y1, B0 = x2 - x1;
  double A1 = y0 - y2, B1 = x0 - x2;
  double A2 = y1 - y0, B2 = x1 - x0;
  double area = (x2 - x0) * A2 - (y2 - y0) * B2;
  bool valid = (fabs(area) > EPSD) && (z0 > EPSD) && (z1 > EPSD) && (z2 > EPSD);
  double s = area;
  double EA0 = 0.0, EB0 = 0.0, EC0 = -1.0;
  double EA1 = 0.0, EB1 = 0.0, EC1 = -1.0;
  double EA2 = 0.0, EB2 = 0.0, EC2 = -1.0;
  double P = 0.0, Q = 0.0, S = 0.0;
  if (valid) {
    EA0 = A0 * s; EB0 = -(B0 * s); EC0 = (y1 * B0 - x1 * A0) * s;
    EA1 = A1 * s; EB1 = -(B1 * s); EC1 = (y2 * B1 - x2 * A1) * s;
    EA2 = A2 * s; EB2 = -(B2 * s); EC2 = (y0 * B2 - x0 * A2) * s;
    double s2 = s * s;
    double R0 = 1.0 / (s2 * fmax(z0, EPSD));
    double R1 = 1.0 / (s2 * fmax(z1, EPSD));
    double R2 = 1.0 / (s2 * fmax(z2, EPSD));
    P = EA0 * R0 + EA1 * R1 + EA2 * R2;
    S = EB0 * R0 + EB1 * R1 + EB2 * R2;
    Q = EC0 * R0 + EC1 * R1 + EC2 * R2;
  }
  double2* T = tri + (size_t)i * 6;
  T[0] = make_double2(EA0, EB0);
  T[1] = make_double2(EC0, EA1);
  T[2] = make_double2(EB1, EC1);
  T[3] = make_double2(EA2, EB2);
  T[4] = make_double2(EC2, P);
  T[5] = make_double2(Q, S);
  float mnx = (float)fmin(x0, fmin(x1, x2));
  float mny = (float)fmin(y0, fmin(y1, y2));
  float mxx = (float)fmax(x0, fmax(x1, x2));
  float mxy = (float)fmax(y0, fmax(y1, y2));
  bbox[i] = make_float4(mnx, mny, mxx, mxy);
}

// center-out rank permutation: i in [0,n) -> position, center first.
// i even -> h + i/2 ; i odd -> h-1 - i/2  (n even, h=n/2). Bijective.
__device__ inline int perm_co(int i, int n) {
  int h = n >> 1;
  return (i & 1) ? (h - 1 - (i >> 1)) : (h + (i >> 1));
}

// broadcast one lane's double to all lanes (scalar) -- zero LDS traffic
__device__ inline double rl_d(double v, int l) {
  int lo = __builtin_amdgcn_readlane(__double2loint(v), l);
  int hi = __builtin_amdgcn_readlane(__double2hiint(v), l);
  return __hiloint2double(hi, lo);
}

// ---------------------------------------------------------------------------
// Kernel 3: PERSISTENT wave-autonomous rasterizer, REGISTER-BROADCAST
// survivor loop, fused interp. 32x16 tiles (512/image): R8's cost is
// ~50/50 corner-cull vs survivor processing, BOTH proportional to tile
// count (cull: every tile-unit scans F/4; survivor: fixed 50-cyc
// readlane+setup cost per (tile,tri) instance). Doubling tile area halves
// both terms; per-pixel work is constant. 8 px/lane: col lane&31, rows
// (lane>>5)*8..+7. Steal order: center-out rank perm on ty (major) and tx
// (minor) -- heavy central rows first, light edge rows last (rect-safe,
// bijective). 1536 blocks = 6/CU (24.6KB LDS). Pipeline, cull
// expressions, readlane broadcast, F-split, merge tie rule, fused interp
// are byte-identical to R8 -> bit-identical output.
// ---------------------------------------------------------------------------
__global__ __launch_bounds__(256, 2) void k_raster(
    const double2* __restrict__ tri,
    const float4* __restrict__ bbox,
    int* __restrict__ counter,
    const double* __restrict__ vpixd,
    const float* __restrict__ vt,
    const int* __restrict__ vi,
    const int* __restrict__ vti,
    const float* __restrict__ tex,
    float* __restrict__ out,
    int N, int V, int F) {
#pragma clang fp contract(off)
  __shared__ __align__(16) char smem[24576];
  double* zbuf = (double*)smem;                    // 4 * 512 * 8 B = 16384
  int* ibuf = (int*)(smem + 16384);                // 4 * 512 * 4 B =  8192
  __shared__ int s_steal;

  int tid = threadIdx.x;
  int w = tid >> 6, lane = tid & 63;
  int xl = lane & 31, yb = (lane >> 5) * 8;
  int FQ = (F + 3) >> 2;
  int fbeg = w * FQ;
  int fend = min(F, fbeg + FQ);
  int NR = (fend > fbeg) ? ((fend - fbeg + 63) >> 6) : 0;
  const int TOT = N * TILES_PER_IMG;
  const int HW = IMG_H * IMG_W;
  const size_t NHW = (size_t)N * HW;
  float* out_render = out;             // (N,3,H,W)
  float* out_mask = out + 3 * NHW;     // (N,H,W)
  float* out_depth = out + 4 * NHW;    // (N,H,W)
  float* out_vt = out + 5 * NHW;       // (N,H,W,2)
  float* out_bary = out + 7 * NHW;     // (N,3,H,W)
  float* out_idx = out + 10 * NHW;     // (N,H,W)

  for (;;) {
    // ---- steal a tile (barrier also guards prior merge reads vs reuse) ----
    if (tid == 0) s_steal = atomicAdd(counter, 1);
    __syncthreads();
    int s = s_steal;
    if (s >= TOT) break;
    int n = s % N;
    int q = s / N;
    int ty = perm_co(q / TILES_X, TILES_Y);   // central rows first
    int tx = perm_co(q % TILES_X, TILES_X);

    int x = tx * TILE_W + xl;
    int ytop = ty * TILE_H;
    double px = (double)x;
    double py0 = (double)(ytop + yb);
    float tminx = (float)(tx * TILE_W) - 0.5f;   // 0.5px guard band
    float tmaxx = tminx + (float)TILE_W;
    float tminy = (float)ytop - 0.5f;
    float tmaxy = tminy + (float)TILE_H;
    double X0 = (double)(tx * TILE_W), X1 = X0 + (double)(TILE_W - 1);
    double Y0 = (double)ytop, Y1 = Y0 + (double)(TILE_H - 1);

    double bz[8];
    int bi[8];
#pragma unroll
    for (int r = 0; r < 8; ++r) { bz[r] = EPSD; bi[r] = -1; }

    const double2* trin = tri + (size_t)n * F * 6;
    const float4* bbn = bbox + (size_t)n * F;

    // ---- pipelined main loop (bbox depth-2, tri depth-1, regs only) ----
    float4 bbB = make_float4(0.f, 0.f, 0.f, 0.f);
    bool bbpA = false;
    double2 A0, A1, A2, A3, A4, A5;
    if (NR > 0) {
      int t0 = fbeg + lane;
      float4 bbA;
      if (t0 < fend) bbA = bbn[t0];
      bbpA = (t0 < fend) &&
             !(bbA.z < tminx || bbA.x > tmaxx || bbA.w < tminy || bbA.y > tmaxy);
      if (bbpA) {
        const double2* T = trin + (size_t)t0 * 6;
        A0 = T[0]; A1 = T[1]; A2 = T[2]; A3 = T[3]; A4 = T[4]; A5 = T[5];
      }
      if (t0 + 64 < fend) bbB = bbn[t0 + 64];
    }
    for (int r = 0; r < NR; ++r) {
      int tbase = fbeg + (r << 6);
      // 1) corner cull for round r from registers (valid where bbpA)
      bool surv = false, full = false;
      if (bbpA) {
        double xs0 = (A0.x >= 0.0) ? X1 : X0;
        double ys0 = (A0.y >= 0.0) ? Y1 : Y0;
        double w0M = fma(ys0, A0.y, fma(xs0, A0.x, A1.x));
        double xs1 = (A1.y >= 0.0) ? X1 : X0;
        double ys1 = (A2.x >= 0.0) ? Y1 : Y0;
        double w1M = fma(ys1, A2.x, fma(xs1, A1.y, A2.y));
        double xs2 = (A3.x >= 0.0) ? X1 : X0;
        double ys2 = (A3.y >= 0.0) ? Y1 : Y0;
        double w2M = fma(ys2, A3.y, fma(xs2, A3.x, A4.x));
        surv = (w0M >= -REJ_SLACK) & (w1M >= -REJ_SLACK) & (w2M >= -REJ_SLACK);
        if (surv) {
          double xn0 = (A0.x >= 0.0) ? X0 : X1;
          double yn0 = (A0.y >= 0.0) ? Y0 : Y1;
          double w0m = fma(yn0, A0.y, fma(xn0, A0.x, A1.x));
          double xn1 = (A1.y >= 0.0) ? X0 : X1;
          double yn1 = (A2.x >= 0.0) ? Y0 : Y1;
          double w1m = fma(yn1, A2.x, fma(xn1, A1.y, A2.y));
          double xn2 = (A3.x >= 0.0) ? X0 : X1;
          double yn2 = (A3.y >= 0.0) ? Y0 : Y1;
          double w2m = fma(yn2, A3.y, fma(xn2, A3.x, A4.x));
          full = (w0m >= FULL_THR) & (w1m >= FULL_THR) & (w2m >= FULL_THR);
        }
      }
      unsigned long long m = __ballot(surv);
      unsigned long long mf = __ballot(surv && full);
      // 2) issue next round's loads into B regs (bbox depth-2 in bbB)
      int tn1 = tbase + 64 + lane;
      bool bbpB = (tn1 < fend) &&
                  !(bbB.z < tminx || bbB.x > tmaxx || bbB.w < tminy || bbB.y > tmaxy);
      double2 B0, B1, B2, B3, B4, B5;
      if (bbpB) {
        const double2* T = trin + (size_t)tn1 * 6;
        B0 = T[0]; B1 = T[1]; B2 = T[2]; B3 = T[3]; B4 = T[4]; B5 = T[5];
      }
      if (tn1 + 64 < fend) bbB = bbn[tn1 + 64];
      // 3) survivors of round r: readlane-broadcast from A regs (no LDS)
      while (m) {
        int src = (int)__builtin_ctzll(m);
        m &= m - 1;
        int ti = tbase + src;
        double P = rl_d(A4.y, src);
        double Qq = rl_d(A5.x, src);
        double S = rl_d(A5.y, src);
        double uu = fma(px, P, Qq);
        if ((mf >> src) & 1ull) {
          // full-cover: no edge tests, zi only
          double py = py0;
#pragma unroll
          for (int rr = 0; rr < 8; ++rr) {
            double zi = fma(py, S, uu);
            if (zi > bz[rr]) { bz[rr] = zi; bi[rr] = ti; }
            py += 1.0;
          }
        } else {
          double EA0 = rl_d(A0.x, src), EB0 = rl_d(A0.y, src);
          double EC0 = rl_d(A1.x, src), EA1 = rl_d(A1.y, src);
          double EB1 = rl_d(A2.x, src), EC1 = rl_d(A2.y, src);
          double EA2 = rl_d(A3.x, src), EB2 = rl_d(A3.y, src);
          double EC2 = rl_d(A4.x, src);
          double q0 = fma(px, EA0, EC0);
          double q1 = fma(px, EA1, EC1);
          double q2 = fma(px, EA2, EC2);
          double py = py0;
#pragma unroll
          for (int rr = 0; rr < 8; ++rr) {
            double W0 = fma(py, EB0, q0);
            double W1 = fma(py, EB1, q1);
            double W2 = fma(py, EB2, q2);
            double zi = fma(py, S, uu);
            int msk = (__double2hiint(W0) | __double2hiint(W1) |
                       __double2hiint(W2)) >> 31;
            zi = __hiloint2double(__double2hiint(zi) | msk, __double2loint(zi));
            if (zi > bz[rr]) { bz[rr] = zi; bi[rr] = ti; }
            py += 1.0;
          }
        }
      }
      // 4) rotate double-buffer (SSA rename, no copies emitted)
      A0 = B0; A1 = B1; A2 = B2; A3 = B3; A4 = B4; A5 = B5;
      bbpA = bbpB;
    }

    // ---- endgame: 4-way merge through LDS ----
    __syncthreads();
#pragma unroll
    for (int r = 0; r < 8; ++r) {
      int pix = (yb + r) * TILE_W + xl;
      zbuf[w * 512 + pix] = bz[r];
      ibuf[w * 512 + pix] = bi[r];
    }
    __syncthreads();
#pragma unroll
    for (int k = 0; k < 2; ++k) {
      int pix = tid + k * 256;
      double z = zbuf[pix];
      int i = ibuf[pix];
#pragma unroll
      for (int qq = 1; qq < 4; ++qq) {
        double zq = zbuf[qq * 512 + pix];
        int iq = ibuf[qq * 512 + pix];
        bool take = (zq > z) || ((zq == z) && ((unsigned)iq < (unsigned)i));
        if (take) { z = zq; i = iq; }
      }
      int yloc = pix >> 5, xloc = pix & 31;
      int y = ytop + yloc;
      int xg = tx * TILE_W + xloc;
      int p = y * IMG_W + xg;
      size_t gid = (size_t)n * HW + p;
      out_idx[gid] = (float)i;

      // ---- fused interpolation + bilinear texture sample ----
      int idx = i;
      if (idx < 0) {
        for (int c = 0; c < 3; ++c) out_render[(size_t)(n * 3 + c) * HW + p] = 0.0f;
        out_mask[gid] = 0.0f;
        out_depth[gid] = 0.0f;
        out_vt[(size_t)gid * 2 + 0] = 0.0f;
        out_vt[(size_t)gid * 2 + 1] = 0.0f;
        for (int kk = 0; kk < 3; ++kk) out_bary[(size_t)(n * 3 + kk) * HW + p] = 0.0f;
      } else {
        int f0 = vi[idx * 3 + 0], f1 = vi[idx * 3 + 1], f2 = vi[idx * 3 + 2];
        int t0i = vti[idx * 3 + 0], t1i = vti[idx * 3 + 1], t2i = vti[idx * 3 + 2];
        const double* pv0 = vpixd + ((size_t)n * V + f0) * 3;
        const double* pv1 = vpixd + ((size_t)n * V + f1) * 3;
        const double* pv2 = vpixd + ((size_t)n * V + f2) * 3;
        float x0 = (float)pv0[0], y0 = (float)pv0[1], z0 = (float)pv0[2];
        float x1 = (float)pv1[0], y1 = (float)pv1[1], z1 = (float)pv1[2];
        float x2 = (float)pv2[0], y2 = (float)pv2[1], z2 = (float)pv2[2];
        float pxf = (float)xg, pyf = (float)y;
        float w0 = (pxf - x1) * (y2 - y1) - (pyf - y1) * (x2 - x1);
        float w1 = (pxf - x2) * (y0 - y2) - (pyf - y2) * (x0 - x2);
        float w2 = (pxf - x0) * (y1 - y0) - (pyf - y0) * (x1 - x0);
        float area = (x2 - x0) * (y1 - y0) - (y2 - y0) * (x1 - x0);
        float sa = (fabsf(area) > EPSF) ? area : 1.0f;
        float b0 = w0 / sa, b1 = w1 / sa, b2 = w2 / sa;
        float zz0 = fmaxf(z0, EPSF), zz1 = fmaxf(z1, EPSF), zz2 = fmaxf(z2, EPSF);
        float bz0 = b0 / zz0, bz1 = b1 / zz1, bz2 = b2 / zz2;
        float zi = fmaxf((bz0 + bz1) + bz2, EPSF);
        float r0 = bz0 / zi, r1 = bz1 / zi, r2 = bz2 / zi;
        float depth = 1.0f / zi;
        float u0 = vt[(size_t)t0i * 2 + 0], q0 = 1.0f - vt[(size_t)t0i * 2 + 1];
        float u1 = vt[(size_t)t1i * 2 + 0], q1 = 1.0f - vt[(size_t)t1i * 2 + 1];
        float u2 = vt[(size_t)t2i * 2 + 0], q2 = 1.0f - vt[(size_t)t2i * 2 + 1];
        float vtx = (r0 * u0 + r1 * u1) + r2 * u2;
        float vty = (r0 * q0 + r1 * q1) + r2 * q2;
        float gx = vtx * 2.0f - 1.0f;
        float gy = vty * 2.0f - 1.0f;
        float ix = ((gx + 1.0f) * 0.5f) * (float)TEX_W - 0.5f;
        float iy = ((gy + 1.0f) * 0.5f) * (float)TEX_H - 0.5f;
        float x0f = floorf(ix), y0f = floorf(iy);
        float fx = ix - x0f, fy = iy - y0f;
        int x0i = min(max((int)x0f, 0), TEX_W - 1);
        int x1i = min(max((int)x0f + 1, 0), TEX_W - 1);
        int y0i = min(max((int)y0f, 0), TEX_H - 1);
        int y1i = min(max((int)y0f + 1, 0), TEX_H - 1);
        float omfx = 1.0f - fx, omfy = 1.0f - fy;
        for (int c = 0; c < 3; ++c) {
          const float* tc = tex + (size_t)(n * 3 + c) * TEX_H * TEX_W;
          float v00 = tc[(size_t)y0i * TEX_W + x0i];
          float v01 = tc[(size_t)y0i * TEX_W + x1i];
          float v10 = tc[(size_t)y1i * TEX_W + x0i];
          float v11 = tc[(size_t)y1i * TEX_W + x1i];
          float o = (v00 * omfx + v01 * fx) * omfy + (v10 * omfx + v11 * fx) * fy;
          out_render[(size_t)(n * 3 + c) * HW + p] = o;
        }
        out_mask[gid] = 1.0f;
        out_depth[gid] = depth;
        out_vt[(size_t)gid * 2 + 0] = vtx;
        out_vt[(size_t)gid * 2 + 1] = vty;
        out_bary[(size_t)(n * 3 + 0) * HW + p] = r0;
        out_bary[(size_t)(n * 3 + 1) * HW + p] = r1;
        out_bary[(size_t)(n * 3 + 2) * HW + p] = r2;
      }
    }
  }
}

// ---------------------------------------------------------------------------
extern "C" void kernel_launch(void* const* d_in, const int* in_sizes, int n_in,
                              void* d_out, int out_size, void* d_ws, size_t ws_size,
                              hipStream_t stream) {
  const float* v = (const float*)d_in[0];
  const float* tex = (const float*)d_in[1];
  const float* vt = (const float*)d_in[2];
  const int* vi = (const int*)d_in[3];
  const int* vti = (const int*)d_in[4];
  const float* campos = (const float*)d_in[5];
  const float* camrot = (const float*)d_in[6];
  const float* focal = (const float*)d_in[7];
  const float* princpt = (const float*)d_in[8];
  int N = in_sizes[5] / 3;            // campos (N,3)
  int V = in_sizes[0] / (3 * N);      // v (N,V,3)
  int F = in_sizes[3] / 3;            // vi (F,3)

  char* wp = (char*)d_ws;
  double* vpixd = (double*)wp;
  wp += sizeof(double) * (size_t)N * V * 3;      // 196608 B
  double2* tri = (double2*)wp;
  wp += sizeof(double2) * (size_t)N * F * 6;     // 393216 B
  float4* bbox = (float4*)wp;
  wp += sizeof(float4) * (size_t)N * F;          //  65536 B
  int* counter = (int*)wp;                       //      4 B

  int nv = N * V;
  k_project<<<(nv + 255) / 256, 256, 0, stream>>>(v, campos, camrot, focal,
                                                  princpt, vpixd, N, V);
  int nf = N * F;
  k_setup<<<(nf + 255) / 256, 256, 0, stream>>>(vpixd, vi, tri, bbox, counter,
                                                N, V, F);
  int nblk = 1536;                     // 6 blocks/CU (24.6 KB LDS)
  int tot = N * TILES_PER_IMG;
  if (nblk > tot) nblk = tot;
  k_raster<<<nblk, 256, 0, stream>>>(tri, bbox, counter, vpixd, vt, vi, vti,
                                     tex, (float*)d_out, N, V, F);
}

// Round 10
// 176.723 us; speedup vs baseline: 1.1076x; 1.1076x over previous
//
#include <hip/hip_runtime.h>
#include <math.h>

#define EPSD 1e-8
#define EPSF 1e-8f
#define IMG_H 512
#define IMG_W 512
#define TEX_W 1024
#define TEX_H 1024
#define REJ_SLACK 1e-3    // reject if corner-max < -REJ_SLACK (>> f64 rounding)
#define FULL_THR 16.0     // full-cover if corner-min >= FULL_THR (>> rounding)
#define TILES_X (IMG_W / 16)
#define TILES_Y (IMG_H / 16)
#define TILES_PER_IMG (TILES_X * TILES_Y)

// ---------------------------------------------------------------------------
// Kernel 1: project vertices in f64 -> vpixd (x_pix, y_pix, z_cam)
// ---------------------------------------------------------------------------
__global__ __launch_bounds__(256) void k_project(
    const float* __restrict__ v,
    const float* __restrict__ campos,
    const float* __restrict__ camrot,
    const float* __restrict__ focal,
    const float* __restrict__ princpt,
    double* __restrict__ vpixd,
    int N, int V) {
#pragma clang fp contract(off)
  int i = blockIdx.x * blockDim.x + threadIdx.x;
  if (i >= N * V) return;
  int n = i / V;
  const float* vv = v + (size_t)i * 3;
  double ax = (double)vv[0] - (double)campos[n * 3 + 0];
  double ay = (double)vv[1] - (double)campos[n * 3 + 1];
  double az = (double)vv[2] - (double)campos[n * 3 + 2];
  const float* R = camrot + (size_t)n * 9;
  double cx = ((double)R[0] * ax + (double)R[1] * ay) + (double)R[2] * az;
  double cy = ((double)R[3] * ax + (double)R[4] * ay) + (double)R[5] * az;
  double cz = ((double)R[6] * ax + (double)R[7] * ay) + (double)R[8] * az;
  double zz = fmax(cz, EPSD);
  double xd = cx / zz;
  double yd = cy / zz;
  const float* Fc = focal + (size_t)n * 4;
  double px = ((double)Fc[0] * xd + (double)Fc[1] * yd) + (double)princpt[n * 2 + 0];
  double py = ((double)Fc[2] * xd + (double)Fc[3] * yd) + (double)princpt[n * 2 + 1];
  vpixd[(size_t)i * 3 + 0] = px;
  vpixd[(size_t)i * 3 + 1] = py;
  vpixd[(size_t)i * 3 + 2] = cz;
}

// ---------------------------------------------------------------------------
// Kernel 2: per-triangle coefficient setup (f64). Also zeroes the steal
// counter (thread 0) -- stream order makes it visible to k_raster.
//   W_k = px*EA_k + py*EB_k + EC_k ; inside <=> all W_k >= 0
//   zi  = px*P + py*S + Q
// Invalid triangles: EA=EB=0, EC=-1 -> never inside, never survives cull.
// Layout per (n,f), 6 x double2:
//  [0]=(EA0,EB0) [1]=(EC0,EA1) [2]=(EB1,EC1) [3]=(EA2,EB2) [4]=(EC2,P) [5]=(Q,S)
// ---------------------------------------------------------------------------
__global__ __launch_bounds__(256) void k_setup(
    const double* __restrict__ vpixd,
    const int* __restrict__ vi,
    double2* __restrict__ tri,
    float4* __restrict__ bbox,
    int* __restrict__ counter,
    int N, int V, int F) {
#pragma clang fp contract(off)
  int i = blockIdx.x * blockDim.x + threadIdx.x;
  if (i == 0) counter[0] = 0;
  if (i >= N * F) return;
  int n = i / F;
  int f = i - n * F;
  int i0 = vi[f * 3 + 0], i1 = vi[f * 3 + 1], i2 = vi[f * 3 + 2];
  const double* p0 = vpixd + ((size_t)n * V + i0) * 3;
  const double* p1 = vpixd + ((size_t)n * V + i1) * 3;
  const double* p2 = vpixd + ((size_t)n * V + i2) * 3;
  double x0 = p0[0], y0 = p0[1], z0 = p0[2];
  double x1 = p1[0], y1 = p1[1], z1 = p1[2];
  double x2 = p2[0], y2 = p2[1], z2 = p2[2];
  double A0 = y2 - y1, B0 = x2 - x1;
  double A1 = y0 - y2, B1 = x0 - x2;
  double A2 = y1 - y0, B2 = x1 - x0;
  double area = (x2 - x0) * A2 - (y2 - y0) * B2;
  bool valid = (fabs(area) > EPSD) && (z0 > EPSD) && (z1 > EPSD) && (z2 > EPSD);
  double s = area;
  double EA0 = 0.0, EB0 = 0.0, EC0 = -1.0;
  double EA1 = 0.0, EB1 = 0.0, EC1 = -1.0;
  double EA2 = 0.0, EB2 = 0.0, EC2 = -1.0;
  double P = 0.0, Q = 0.0, S = 0.0;
  if (valid) {
    EA0 = A0 * s; EB0 = -(B0 * s); EC0 = (y1 * B0 - x1 * A0) * s;
    EA1 = A1 * s; EB1 = -(B1 * s); EC1 = (y2 * B1 - x2 * A1) * s;
    EA2 = A2 * s; EB2 = -(B2 * s); EC2 = (y0 * B2 - x0 * A2) * s;
    double s2 = s * s;
    double R0 = 1.0 / (s2 * fmax(z0, EPSD));
    double R1 = 1.0 / (s2 * fmax(z1, EPSD));
    double R2 = 1.0 / (s2 * fmax(z2, EPSD));
    P = EA0 * R0 + EA1 * R1 + EA2 * R2;
    S = EB0 * R0 + EB1 * R1 + EB2 * R2;
    Q = EC0 * R0 + EC1 * R1 + EC2 * R2;
  }
  double2* T = tri + (size_t)i * 6;
  T[0] = make_double2(EA0, EB0);
  T[1] = make_double2(EC0, EA1);
  T[2] = make_double2(EB1, EC1);
  T[3] = make_double2(EA2, EB2);
  T[4] = make_double2(EC2, P);
  T[5] = make_double2(Q, S);
  float mnx = (float)fmin(x0, fmin(x1, x2));
  float mny = (float)fmin(y0, fmin(y1, y2));
  float mxx = (float)fmax(x0, fmax(x1, x2));
  float mxy = (float)fmax(y0, fmax(y1, y2));
  bbox[i] = make_float4(mnx, mny, mxx, mxy);
}

// Map steal order s (0-based) -> tile (tx,ty), walking square rings outward
// from the image center. Heavy (central) tiles are stolen FIRST so they run
// concurrently from t=0 and the kernel tail is the light edge tiles.
// Ring k (k=0..15): side L=2k+2, 8k+4 tiles, cumulative start 4k^2.
__device__ inline void steal_to_tile(int s, int& tx, int& ty) {
  int k = (int)(__fsqrt_rn((float)s) * 0.5f);
  while (k > 0 && 4 * k * k > s) --k;
  while (4 * (k + 1) * (k + 1) <= s) ++k;
  int o = s - 4 * k * k;
  int L = 2 * k + 2;
  int x0 = TILES_X / 2 - 1 - k, y0 = TILES_Y / 2 - 1 - k;
  int side = o / (L - 1);
  int off = o - side * (L - 1);
  if (side == 0)      { tx = x0 + off;         ty = y0; }
  else if (side == 1) { tx = x0 + L - 1;       ty = y0 + off; }
  else if (side == 2) { tx = x0 + L - 1 - off; ty = y0 + L - 1; }
  else                { tx = x0;               ty = y0 + L - 1 - off; }
}

// broadcast one lane's double to all lanes (scalar) -- zero LDS traffic
__device__ inline double rl_d(double v, int l) {
  int lo = __builtin_amdgcn_readlane(__double2loint(v), l);
  int hi = __builtin_amdgcn_readlane(__double2hiint(v), l);
  return __hiloint2double(hi, lo);
}

// ---------------------------------------------------------------------------
// Kernel 3: PERSISTENT wave-autonomous rasterizer, REGISTER-BROADCAST
// survivor loop, DEPTH-2 tri prefetch, fused interp. R8 frame verbatim
// (16x16 tiles, 4 waves split F, center-first ring stealing, readlane
// survivor broadcast, LDS endgame merge, fused interp) with ONE change:
// the tri-coefficient load pipeline is deepened from depth-1 to depth-2
// (A/B/C register sets; bbox runs depth-3). R8 stalled ~48% of cycles
// with 4 resident waves/SIMD because the depth-1 tri load (~200-400cyc
// L2) was covered by only ~150cyc of work on low-survivor rounds; at
// depth-2 each load has two cull+survivor phases to hide under.
// Survivor order (lane asc within round, rounds asc) + strict zi> keeps
// the reference first-at-min tie rule exactly. Output bit-identical.
// ---------------------------------------------------------------------------
__global__ __launch_bounds__(256, 2) void k_raster(
    const double2* __restrict__ tri,
    const float4* __restrict__ bbox,
    int* __restrict__ counter,
    const double* __restrict__ vpixd,
    const float* __restrict__ vt,
    const int* __restrict__ vi,
    const int* __restrict__ vti,
    const float* __restrict__ tex,
    float* __restrict__ out,
    int N, int V, int F) {
#pragma clang fp contract(off)
  __shared__ __align__(16) char smem[12288];
  double* zbuf = (double*)smem;                    // 4 * 256 * 8 B = 8192
  int* ibuf = (int*)(smem + 8192);                 // 4 * 256 * 4 B = 4096
  __shared__ int s_steal;

  int tid = threadIdx.x;
  int w = tid >> 6, lane = tid & 63;
  int xl = lane & 15, yb = (lane >> 4) * 4;
  int FQ = (F + 3) >> 2;
  int fbeg = w * FQ;
  int fend = min(F, fbeg + FQ);
  int NR = (fend > fbeg) ? ((fend - fbeg + 63) >> 6) : 0;
  const int TOT = N * TILES_PER_IMG;
  const int HW = IMG_H * IMG_W;
  const size_t NHW = (size_t)N * HW;
  float* out_render = out;             // (N,3,H,W)
  float* out_mask = out + 3 * NHW;     // (N,H,W)
  float* out_depth = out + 4 * NHW;    // (N,H,W)
  float* out_vt = out + 5 * NHW;       // (N,H,W,2)
  float* out_bary = out + 7 * NHW;     // (N,3,H,W)
  float* out_idx = out + 10 * NHW;     // (N,H,W)

  for (;;) {
    // ---- steal a tile (barrier also guards prior merge reads vs reuse) ----
    if (tid == 0) s_steal = atomicAdd(counter, 1);
    __syncthreads();
    int s = s_steal;
    if (s >= TOT) break;
    int n = s % N;
    int q = s / N;
    int tx, ty;
    steal_to_tile(q, tx, ty);

    int x = tx * 16 + xl;
    int ytop = ty * 16;
    double px = (double)x;
    double py0 = (double)(ytop + yb);
    float tminx = (float)(tx * 16) - 0.5f;   // 0.5px guard band
    float tmaxx = tminx + 16.0f;
    float tminy = (float)ytop - 0.5f;
    float tmaxy = tminy + 16.0f;
    double X0 = (double)(tx * 16), X1 = X0 + 15.0;
    double Y0 = (double)ytop, Y1 = Y0 + 15.0;

    double bz[4];
    int bi[4];
#pragma unroll
    for (int r = 0; r < 4; ++r) { bz[r] = EPSD; bi[r] = -1; }

    const double2* trin = tri + (size_t)n * F * 6;
    const float4* bbn = bbox + (size_t)n * F;

    // ---- pipelined main loop: tri depth-2 (A,B,C), bbox depth-3 ----
    bool pA = false, pB = false;
    double2 A0, A1, A2, A3, A4, A5;
    double2 B0, B1, B2, B3, B4, B5;
    float4 bbC = make_float4(0.f, 0.f, 0.f, 0.f);
    if (NR > 0) {
      int t0 = fbeg + lane;
      float4 bbA;
      if (t0 < fend) bbA = bbn[t0];
      pA = (t0 < fend) &&
           !(bbA.z < tminx || bbA.x > tmaxx || bbA.w < tminy || bbA.y > tmaxy);
      if (pA) {
        const double2* T = trin + (size_t)t0 * 6;
        A0 = T[0]; A1 = T[1]; A2 = T[2]; A3 = T[3]; A4 = T[4]; A5 = T[5];
      }
      int t1 = t0 + 64;
      float4 bbB;
      if (t1 < fend) bbB = bbn[t1];
      pB = (t1 < fend) &&
           !(bbB.z < tminx || bbB.x > tmaxx || bbB.w < tminy || bbB.y > tmaxy);
      if (pB) {
        const double2* T = trin + (size_t)t1 * 6;
        B0 = T[0]; B1 = T[1]; B2 = T[2]; B3 = T[3]; B4 = T[4]; B5 = T[5];
      }
      if (t0 + 128 < fend) bbC = bbn[t0 + 128];
    }
    for (int r = 0; r < NR; ++r) {
      int tbase = fbeg + (r << 6);
      // 1) corner cull for round r from A regs (valid where pA)
      bool surv = false, full = false;
      if (pA) {
        double xs0 = (A0.x >= 0.0) ? X1 : X0;
        double ys0 = (A0.y >= 0.0) ? Y1 : Y0;
        double w0M = fma(ys0, A0.y, fma(xs0, A0.x, A1.x));
        double xs1 = (A1.y >= 0.0) ? X1 : X0;
        double ys1 = (A2.x >= 0.0) ? Y1 : Y0;
        double w1M = fma(ys1, A2.x, fma(xs1, A1.y, A2.y));
        double xs2 = (A3.x >= 0.0) ? X1 : X0;
        double ys2 = (A3.y >= 0.0) ? Y1 : Y0;
        double w2M = fma(ys2, A3.y, fma(xs2, A3.x, A4.x));
        surv = (w0M >= -REJ_SLACK) & (w1M >= -REJ_SLACK) & (w2M >= -REJ_SLACK);
        if (surv) {
          double xn0 = (A0.x >= 0.0) ? X0 : X1;
          double yn0 = (A0.y >= 0.0) ? Y0 : Y1;
          double w0m = fma(yn0, A0.y, fma(xn0, A0.x, A1.x));
          double xn1 = (A1.y >= 0.0) ? X0 : X1;
          double yn1 = (A2.x >= 0.0) ? Y0 : Y1;
          double w1m = fma(yn1, A2.x, fma(xn1, A1.y, A2.y));
          double xn2 = (A3.x >= 0.0) ? X0 : X1;
          double yn2 = (A3.y >= 0.0) ? Y0 : Y1;
          double w2m = fma(yn2, A3.y, fma(xn2, A3.x, A4.x));
          full = (w0m >= FULL_THR) & (w1m >= FULL_THR) & (w2m >= FULL_THR);
        }
      }
      unsigned long long m = __ballot(surv);
      unsigned long long mf = __ballot(surv && full);
      // 2) issue round r+2 loads into C regs (bbox depth-3 in bbC)
      int tn2 = tbase + 128 + lane;
      bool pC = (tn2 < fend) &&
                !(bbC.z < tminx || bbC.x > tmaxx || bbC.w < tminy || bbC.y > tmaxy);
      double2 C0, C1, C2, C3, C4, C5;
      if (pC) {
        const double2* T = trin + (size_t)tn2 * 6;
        C0 = T[0]; C1 = T[1]; C2 = T[2]; C3 = T[3]; C4 = T[4]; C5 = T[5];
      }
      if (tn2 + 64 < fend) bbC = bbn[tn2 + 64];
      // 3) survivors of round r: readlane-broadcast from A regs (no LDS)
      while (m) {
        int src = (int)__builtin_ctzll(m);
        m &= m - 1;
        int ti = tbase + src;
        double P = rl_d(A4.y, src);
        double Qq = rl_d(A5.x, src);
        double S = rl_d(A5.y, src);
        double uu = fma(px, P, Qq);
        if ((mf >> src) & 1ull) {
          // full-cover: no edge tests, zi only
          double py = py0;
#pragma unroll
          for (int rr = 0; rr < 4; ++rr) {
            double zi = fma(py, S, uu);
            if (zi > bz[rr]) { bz[rr] = zi; bi[rr] = ti; }
            py += 1.0;
          }
        } else {
          double EA0 = rl_d(A0.x, src), EB0 = rl_d(A0.y, src);
          double EC0 = rl_d(A1.x, src), EA1 = rl_d(A1.y, src);
          double EB1 = rl_d(A2.x, src), EC1 = rl_d(A2.y, src);
          double EA2 = rl_d(A3.x, src), EB2 = rl_d(A3.y, src);
          double EC2 = rl_d(A4.x, src);
          double q0 = fma(px, EA0, EC0);
          double q1 = fma(px, EA1, EC1);
          double q2 = fma(px, EA2, EC2);
          double py = py0;
#pragma unroll
          for (int rr = 0; rr < 4; ++rr) {
            double W0 = fma(py, EB0, q0);
            double W1 = fma(py, EB1, q1);
            double W2 = fma(py, EB2, q2);
            double zi = fma(py, S, uu);
            int msk = (__double2hiint(W0) | __double2hiint(W1) |
                       __double2hiint(W2)) >> 31;
            zi = __hiloint2double(__double2hiint(zi) | msk, __double2loint(zi));
            if (zi > bz[rr]) { bz[rr] = zi; bi[rr] = ti; }
            py += 1.0;
          }
        }
      }
      // 4) rotate pipeline (SSA rename, no copies emitted)
      A0 = B0; A1 = B1; A2 = B2; A3 = B3; A4 = B4; A5 = B5; pA = pB;
      B0 = C0; B1 = C1; B2 = C2; B3 = C3; B4 = C4; B5 = C5; pB = pC;
    }

    // ---- endgame: 4-way merge through LDS ----
    __syncthreads();
#pragma unroll
    for (int r = 0; r < 4; ++r) {
      int pix = (yb + r) * 16 + xl;
      zbuf[w * 256 + pix] = bz[r];
      ibuf[w * 256 + pix] = bi[r];
    }
    __syncthreads();
    {
      int pix = tid;
      double z = zbuf[pix];
      int i = ibuf[pix];
#pragma unroll
      for (int qq = 1; qq < 4; ++qq) {
        double zq = zbuf[qq * 256 + pix];
        int iq = ibuf[qq * 256 + pix];
        bool take = (zq > z) || ((zq == z) && ((unsigned)iq < (unsigned)i));
        if (take) { z = zq; i = iq; }
      }
      int yloc = pix >> 4, xloc = pix & 15;
      int y = ytop + yloc;
      int xg = tx * 16 + xloc;
      int p = y * IMG_W + xg;
      size_t gid = (size_t)n * HW + p;
      out_idx[gid] = (float)i;

      // ---- fused interpolation + bilinear texture sample ----
      int idx = i;
      if (idx < 0) {
        for (int c = 0; c < 3; ++c) out_render[(size_t)(n * 3 + c) * HW + p] = 0.0f;
        out_mask[gid] = 0.0f;
        out_depth[gid] = 0.0f;
        out_vt[(size_t)gid * 2 + 0] = 0.0f;
        out_vt[(size_t)gid * 2 + 1] = 0.0f;
        for (int k = 0; k < 3; ++k) out_bary[(size_t)(n * 3 + k) * HW + p] = 0.0f;
      } else {
        int f0 = vi[idx * 3 + 0], f1 = vi[idx * 3 + 1], f2 = vi[idx * 3 + 2];
        int t0i = vti[idx * 3 + 0], t1i = vti[idx * 3 + 1], t2i = vti[idx * 3 + 2];
        const double* pv0 = vpixd + ((size_t)n * V + f0) * 3;
        const double* pv1 = vpixd + ((size_t)n * V + f1) * 3;
        const double* pv2 = vpixd + ((size_t)n * V + f2) * 3;
        float x0 = (float)pv0[0], y0 = (float)pv0[1], z0 = (float)pv0[2];
        float x1 = (float)pv1[0], y1 = (float)pv1[1], z1 = (float)pv1[2];
        float x2 = (float)pv2[0], y2 = (float)pv2[1], z2 = (float)pv2[2];
        float pxf = (float)xg, pyf = (float)y;
        float w0 = (pxf - x1) * (y2 - y1) - (pyf - y1) * (x2 - x1);
        float w1 = (pxf - x2) * (y0 - y2) - (pyf - y2) * (x0 - x2);
        float w2 = (pxf - x0) * (y1 - y0) - (pyf - y0) * (x1 - x0);
        float area = (x2 - x0) * (y1 - y0) - (y2 - y0) * (x1 - x0);
        float sa = (fabsf(area) > EPSF) ? area : 1.0f;
        float b0 = w0 / sa, b1 = w1 / sa, b2 = w2 / sa;
        float zz0 = fmaxf(z0, EPSF), zz1 = fmaxf(z1, EPSF), zz2 = fmaxf(z2, EPSF);
        float bz0 = b0 / zz0, bz1 = b1 / zz1, bz2 = b2 / zz2;
        float zi = fmaxf((bz0 + bz1) + bz2, EPSF);
        float r0 = bz0 / zi, r1 = bz1 / zi, r2 = bz2 / zi;
        float depth = 1.0f / zi;
        float u0 = vt[(size_t)t0i * 2 + 0], q0 = 1.0f - vt[(size_t)t0i * 2 + 1];
        float u1 = vt[(size_t)t1i * 2 + 0], q1 = 1.0f - vt[(size_t)t1i * 2 + 1];
        float u2 = vt[(size_t)t2i * 2 + 0], q2 = 1.0f - vt[(size_t)t2i * 2 + 1];
        float vtx = (r0 * u0 + r1 * u1) + r2 * u2;
        float vty = (r0 * q0 + r1 * q1) + r2 * q2;
        float gx = vtx * 2.0f - 1.0f;
        float gy = vty * 2.0f - 1.0f;
        float ix = ((gx + 1.0f) * 0.5f) * (float)TEX_W - 0.5f;
        float iy = ((gy + 1.0f) * 0.5f) * (float)TEX_H - 0.5f;
        float x0f = floorf(ix), y0f = floorf(iy);
        float fx = ix - x0f, fy = iy - y0f;
        int x0i = min(max((int)x0f, 0), TEX_W - 1);
        int x1i = min(max((int)x0f + 1, 0), TEX_W - 1);
        int y0i = min(max((int)y0f, 0), TEX_H - 1);
        int y1i = min(max((int)y0f + 1, 0), TEX_H - 1);
        float omfx = 1.0f - fx, omfy = 1.0f - fy;
        for (int c = 0; c < 3; ++c) {
          const float* tc = tex + (size_t)(n * 3 + c) * TEX_H * TEX_W;
          float v00 = tc[(size_t)y0i * TEX_W + x0i];
          float v01 = tc[(size_t)y0i * TEX_W + x1i];
          float v10 = tc[(size_t)y1i * TEX_W + x0i];
          float v11 = tc[(size_t)y1i * TEX_W + x1i];
          float o = (v00 * omfx + v01 * fx) * omfy + (v10 * omfx + v11 * fx) * fy;
          out_render[(size_t)(n * 3 + c) * HW + p] = o;
        }
        out_mask[gid] = 1.0f;
        out_depth[gid] = depth;
        out_vt[(size_t)gid * 2 + 0] = vtx;
        out_vt[(size_t)gid * 2 + 1] = vty;
        out_bary[(size_t)(n * 3 + 0) * HW + p] = r0;
        out_bary[(size_t)(n * 3 + 1) * HW + p] = r1;
        out_bary[(size_t)(n * 3 + 2) * HW + p] = r2;
      }
    }
  }
}

// ---------------------------------------------------------------------------
extern "C" void kernel_launch(void* const* d_in, const int* in_sizes, int n_in,
                              void* d_out, int out_size, void* d_ws, size_t ws_size,
                              hipStream_t stream) {
  const float* v = (const float*)d_in[0];
  const float* tex = (const float*)d_in[1];
  const float* vt = (const float*)d_in[2];
  const int* vi = (const int*)d_in[3];
  const int* vti = (const int*)d_in[4];
  const float* campos = (const float*)d_in[5];
  const float* camrot = (const float*)d_in[6];
  const float* focal = (const float*)d_in[7];
  const float* princpt = (const float*)d_in[8];
  int N = in_sizes[5] / 3;            // campos (N,3)
  int V = in_sizes[0] / (3 * N);      // v (N,V,3)
  int F = in_sizes[3] / 3;            // vi (F,3)

  char* wp = (char*)d_ws;
  double* vpixd = (double*)wp;
  wp += sizeof(double) * (size_t)N * V * 3;      // 196608 B
  double2* tri = (double2*)wp;
  wp += sizeof(double2) * (size_t)N * F * 6;     // 393216 B
  float4* bbox = (float4*)wp;
  wp += sizeof(float4) * (size_t)N * F;          //  65536 B
  int* counter = (int*)wp;                       //      4 B

  int nv = N * V;
  k_project<<<(nv + 255) / 256, 256, 0, stream>>>(v, campos, camrot, focal,
                                                  princpt, vpixd, N, V);
  int nf = N * F;
  k_setup<<<(nf + 255) / 256, 256, 0, stream>>>(vpixd, vi, tri, bbox, counter,
                                                N, V, F);
  int nblk = 1024;                     // 4 blocks/CU resident
  int tot = N * TILES_PER_IMG;
  if (nblk > tot) nblk = tot;
  k_raster<<<nblk, 256, 0, stream>>>(tri, bbox, counter, vpixd, vt, vi, vti,
                                     tex, (float*)d_out, N, V, F);
}

// Round 11
// 166.880 us; speedup vs baseline: 1.1730x; 1.0590x over previous
//
#include <hip/hip_runtime.h>
#include <math.h>

#define EPSD 1e-8
#define EPSF 1e-8f
#define IMG_H 512
#define IMG_W 512
#define TEX_W 1024
#define TEX_H 1024
#define REJ_SLACK 1e-3    // reject if corner-max < -REJ_SLACK (>> f64 rounding)
#define FULL_THR 16.0     // full-cover if corner-min >= FULL_THR (>> rounding)
#define TILES_X (IMG_W / 16)
#define TILES_Y (IMG_H / 16)
#define TILES_PER_IMG (TILES_X * TILES_Y)

// ---------------------------------------------------------------------------
// Kernel 1: project vertices in f64 -> vpixd (x_pix, y_pix, z_cam)
// ---------------------------------------------------------------------------
__global__ __launch_bounds__(256) void k_project(
    const float* __restrict__ v,
    const float* __restrict__ campos,
    const float* __restrict__ camrot,
    const float* __restrict__ focal,
    const float* __restrict__ princpt,
    double* __restrict__ vpixd,
    int N, int V) {
#pragma clang fp contract(off)
  int i = blockIdx.x * blockDim.x + threadIdx.x;
  if (i >= N * V) return;
  int n = i / V;
  const float* vv = v + (size_t)i * 3;
  double ax = (double)vv[0] - (double)campos[n * 3 + 0];
  double ay = (double)vv[1] - (double)campos[n * 3 + 1];
  double az = (double)vv[2] - (double)campos[n * 3 + 2];
  const float* R = camrot + (size_t)n * 9;
  double cx = ((double)R[0] * ax + (double)R[1] * ay) + (double)R[2] * az;
  double cy = ((double)R[3] * ax + (double)R[4] * ay) + (double)R[5] * az;
  double cz = ((double)R[6] * ax + (double)R[7] * ay) + (double)R[8] * az;
  double zz = fmax(cz, EPSD);
  double xd = cx / zz;
  double yd = cy / zz;
  const float* Fc = focal + (size_t)n * 4;
  double px = ((double)Fc[0] * xd + (double)Fc[1] * yd) + (double)princpt[n * 2 + 0];
  double py = ((double)Fc[2] * xd + (double)Fc[3] * yd) + (double)princpt[n * 2 + 1];
  vpixd[(size_t)i * 3 + 0] = px;
  vpixd[(size_t)i * 3 + 1] = py;
  vpixd[(size_t)i * 3 + 2] = cz;
}

// ---------------------------------------------------------------------------
// Kernel 2: per-triangle coefficient setup (f64). Also zeroes the steal
// counter (thread 0) -- stream order makes it visible to k_raster.
//   W_k = px*EA_k + py*EB_k + EC_k ; inside <=> all W_k >= 0
//   zi  = px*P + py*S + Q
// Invalid triangles: EA=EB=0, EC=-1 -> never inside, never survives cull.
// SoA layout (6 planes of double2, plane stride NF = N*F):
//  plane0[i]=(EA0,EB0) plane1[i]=(EC0,EA1) plane2[i]=(EB1,EC1)
//  plane3[i]=(EA2,EB2) plane4[i]=(EC2,P)   plane5[i]=(Q,S)
// AoS (96 B/tri) made every cull-phase load instruction touch ~48 cache
// lines (lane stride 96 B); SoA coalesces each to ~6 lines.
// ---------------------------------------------------------------------------
__global__ __launch_bounds__(256) void k_setup(
    const double* __restrict__ vpixd,
    const int* __restrict__ vi,
    double2* __restrict__ tri,
    float4* __restrict__ bbox,
    int* __restrict__ counter,
    int N, int V, int F) {
#pragma clang fp contract(off)
  int i = blockIdx.x * blockDim.x + threadIdx.x;
  if (i == 0) counter[0] = 0;
  if (i >= N * F) return;
  int n = i / F;
  int f = i - n * F;
  int i0 = vi[f * 3 + 0], i1 = vi[f * 3 + 1], i2 = vi[f * 3 + 2];
  const double* p0 = vpixd + ((size_t)n * V + i0) * 3;
  const double* p1 = vpixd + ((size_t)n * V + i1) * 3;
  const double* p2 = vpixd + ((size_t)n * V + i2) * 3;
  double x0 = p0[0], y0 = p0[1], z0 = p0[2];
  double x1 = p1[0], y1 = p1[1], z1 = p1[2];
  double x2 = p2[0], y2 = p2[1], z2 = p2[2];
  double A0 = y2 - y1, B0 = x2 - x1;
  double A1 = y0 - y2, B1 = x0 - x2;
  double A2 = y1 - y0, B2 = x1 - x0;
  double area = (x2 - x0) * A2 - (y2 - y0) * B2;
  bool valid = (fabs(area) > EPSD) && (z0 > EPSD) && (z1 > EPSD) && (z2 > EPSD);
  double s = area;
  double EA0 = 0.0, EB0 = 0.0, EC0 = -1.0;
  double EA1 = 0.0, EB1 = 0.0, EC1 = -1.0;
  double EA2 = 0.0, EB2 = 0.0, EC2 = -1.0;
  double P = 0.0, Q = 0.0, S = 0.0;
  if (valid) {
    EA0 = A0 * s; EB0 = -(B0 * s); EC0 = (y1 * B0 - x1 * A0) * s;
    EA1 = A1 * s; EB1 = -(B1 * s); EC1 = (y2 * B1 - x2 * A1) * s;
    EA2 = A2 * s; EB2 = -(B2 * s); EC2 = (y0 * B2 - x0 * A2) * s;
    double s2 = s * s;
    double R0 = 1.0 / (s2 * fmax(z0, EPSD));
    double R1 = 1.0 / (s2 * fmax(z1, EPSD));
    double R2 = 1.0 / (s2 * fmax(z2, EPSD));
    P = EA0 * R0 + EA1 * R1 + EA2 * R2;
    S = EB0 * R0 + EB1 * R1 + EB2 * R2;
    Q = EC0 * R0 + EC1 * R1 + EC2 * R2;
  }
  size_t NF = (size_t)N * F;
  tri[i] = make_double2(EA0, EB0);
  tri[NF + i] = make_double2(EC0, EA1);
  tri[2 * NF + i] = make_double2(EB1, EC1);
  tri[3 * NF + i] = make_double2(EA2, EB2);
  tri[4 * NF + i] = make_double2(EC2, P);
  tri[5 * NF + i] = make_double2(Q, S);
  float mnx = (float)fmin(x0, fmin(x1, x2));
  float mny = (float)fmin(y0, fmin(y1, y2));
  float mxx = (float)fmax(x0, fmax(x1, x2));
  float mxy = (float)fmax(y0, fmax(y1, y2));
  bbox[i] = make_float4(mnx, mny, mxx, mxy);
}

// Map steal order s (0-based) -> tile (tx,ty), walking square rings outward
// from the image center. Heavy (central) tiles are stolen FIRST so they run
// concurrently from t=0 and the kernel tail is the light edge tiles.
// Ring k (k=0..15): side L=2k+2, 8k+4 tiles, cumulative start 4k^2.
__device__ inline void steal_to_tile(int s, int& tx, int& ty) {
  int k = (int)(__fsqrt_rn((float)s) * 0.5f);
  while (k > 0 && 4 * k * k > s) --k;
  while (4 * (k + 1) * (k + 1) <= s) ++k;
  int o = s - 4 * k * k;
  int L = 2 * k + 2;
  int x0 = TILES_X / 2 - 1 - k, y0 = TILES_Y / 2 - 1 - k;
  int side = o / (L - 1);
  int off = o - side * (L - 1);
  if (side == 0)      { tx = x0 + off;         ty = y0; }
  else if (side == 1) { tx = x0 + L - 1;       ty = y0 + off; }
  else if (side == 2) { tx = x0 + L - 1 - off; ty = y0 + L - 1; }
  else                { tx = x0;               ty = y0 + L - 1 - off; }
}

// broadcast one lane's double to all lanes (scalar) -- zero LDS traffic
__device__ inline double rl_d(double v, int l) {
  int lo = __builtin_amdgcn_readlane(__double2loint(v), l);
  int hi = __builtin_amdgcn_readlane(__double2hiint(v), l);
  return __hiloint2double(hi, lo);
}

// ---------------------------------------------------------------------------
// Kernel 3: PERSISTENT wave-autonomous rasterizer, REGISTER-BROADCAST
// survivor loop, fused interp — R8 structure verbatim (16x16 tiles, 4
// waves split F, center-first ring stealing, depth-1 A/B pipeline,
// readlane survivor broadcast, LDS endgame merge, fused interp) with the
// tri array accessed in SoA form: cull-phase loads are now fully
// coalesced (lane stride 16 B per plane instead of 96 B AoS), cutting
// per-instruction L2 transactions ~8x — the stall source R10's deeper
// pipeline could not fix. Numerics byte-identical -> output identical.
// Winner rule == reference: max zi, first-at-min tie via scan order.
// ---------------------------------------------------------------------------
__global__ __launch_bounds__(256, 2) void k_raster(
    const double2* __restrict__ tri,
    const float4* __restrict__ bbox,
    int* __restrict__ counter,
    const double* __restrict__ vpixd,
    const float* __restrict__ vt,
    const int* __restrict__ vi,
    const int* __restrict__ vti,
    const float* __restrict__ tex,
    float* __restrict__ out,
    int N, int V, int F) {
#pragma clang fp contract(off)
  __shared__ __align__(16) char smem[12288];
  double* zbuf = (double*)smem;                    // 4 * 256 * 8 B = 8192
  int* ibuf = (int*)(smem + 8192);                 // 4 * 256 * 4 B = 4096
  __shared__ int s_steal;

  int tid = threadIdx.x;
  int w = tid >> 6, lane = tid & 63;
  int xl = lane & 15, yb = (lane >> 4) * 4;
  int FQ = (F + 3) >> 2;
  int fbeg = w * FQ;
  int fend = min(F, fbeg + FQ);
  int NR = (fend > fbeg) ? ((fend - fbeg + 63) >> 6) : 0;
  const int TOT = N * TILES_PER_IMG;
  const int HW = IMG_H * IMG_W;
  const size_t NHW = (size_t)N * HW;
  const size_t NF = (size_t)N * F;
  float* out_render = out;             // (N,3,H,W)
  float* out_mask = out + 3 * NHW;     // (N,H,W)
  float* out_depth = out + 4 * NHW;    // (N,H,W)
  float* out_vt = out + 5 * NHW;       // (N,H,W,2)
  float* out_bary = out + 7 * NHW;     // (N,3,H,W)
  float* out_idx = out + 10 * NHW;     // (N,H,W)

  for (;;) {
    // ---- steal a tile (barrier also guards prior merge reads vs reuse) ----
    if (tid == 0) s_steal = atomicAdd(counter, 1);
    __syncthreads();
    int s = s_steal;
    if (s >= TOT) break;
    int n = s % N;
    int q = s / N;
    int tx, ty;
    steal_to_tile(q, tx, ty);

    int x = tx * 16 + xl;
    int ytop = ty * 16;
    double px = (double)x;
    double py0 = (double)(ytop + yb);
    float tminx = (float)(tx * 16) - 0.5f;   // 0.5px guard band
    float tmaxx = tminx + 16.0f;
    float tminy = (float)ytop - 0.5f;
    float tmaxy = tminy + 16.0f;
    double X0 = (double)(tx * 16), X1 = X0 + 15.0;
    double Y0 = (double)ytop, Y1 = Y0 + 15.0;

    double bz[4];
    int bi[4];
#pragma unroll
    for (int r = 0; r < 4; ++r) { bz[r] = EPSD; bi[r] = -1; }

    const double2* trin = tri + (size_t)n * F;   // plane-0 base for image n
    const float4* bbn = bbox + (size_t)n * F;

    // ---- pipelined main loop (bbox depth-2, tri depth-1, regs only) ----
    float4 bbB = make_float4(0.f, 0.f, 0.f, 0.f);
    bool bbpA = false;
    double2 A0, A1, A2, A3, A4, A5;
    if (NR > 0) {
      int t0 = fbeg + lane;
      float4 bbA;
      if (t0 < fend) bbA = bbn[t0];
      bbpA = (t0 < fend) &&
             !(bbA.z < tminx || bbA.x > tmaxx || bbA.w < tminy || bbA.y > tmaxy);
      if (bbpA) {
        const double2* T = trin + t0;
        A0 = T[0]; A1 = T[NF]; A2 = T[2 * NF];
        A3 = T[3 * NF]; A4 = T[4 * NF]; A5 = T[5 * NF];
      }
      if (t0 + 64 < fend) bbB = bbn[t0 + 64];
    }
    for (int r = 0; r < NR; ++r) {
      int tbase = fbeg + (r << 6);
      // 1) corner cull for round r from registers (valid where bbpA)
      bool surv = false, full = false;
      if (bbpA) {
        double xs0 = (A0.x >= 0.0) ? X1 : X0;
        double ys0 = (A0.y >= 0.0) ? Y1 : Y0;
        double w0M = fma(ys0, A0.y, fma(xs0, A0.x, A1.x));
        double xs1 = (A1.y >= 0.0) ? X1 : X0;
        double ys1 = (A2.x >= 0.0) ? Y1 : Y0;
        double w1M = fma(ys1, A2.x, fma(xs1, A1.y, A2.y));
        double xs2 = (A3.x >= 0.0) ? X1 : X0;
        double ys2 = (A3.y >= 0.0) ? Y1 : Y0;
        double w2M = fma(ys2, A3.y, fma(xs2, A3.x, A4.x));
        surv = (w0M >= -REJ_SLACK) & (w1M >= -REJ_SLACK) & (w2M >= -REJ_SLACK);
        if (surv) {
          double xn0 = (A0.x >= 0.0) ? X0 : X1;
          double yn0 = (A0.y >= 0.0) ? Y0 : Y1;
          double w0m = fma(yn0, A0.y, fma(xn0, A0.x, A1.x));
          double xn1 = (A1.y >= 0.0) ? X0 : X1;
          double yn1 = (A2.x >= 0.0) ? Y0 : Y1;
          double w1m = fma(yn1, A2.x, fma(xn1, A1.y, A2.y));
          double xn2 = (A3.x >= 0.0) ? X0 : X1;
          double yn2 = (A3.y >= 0.0) ? Y0 : Y1;
          double w2m = fma(yn2, A3.y, fma(xn2, A3.x, A4.x));
          full = (w0m >= FULL_THR) & (w1m >= FULL_THR) & (w2m >= FULL_THR);
        }
      }
      unsigned long long m = __ballot(surv);
      unsigned long long mf = __ballot(surv && full);
      // 2) issue next round's loads into B regs (bbox depth-2 in bbB)
      int tn1 = tbase + 64 + lane;
      bool bbpB = (tn1 < fend) &&
                  !(bbB.z < tminx || bbB.x > tmaxx || bbB.w < tminy || bbB.y > tmaxy);
      double2 B0, B1, B2, B3, B4, B5;
      if (bbpB) {
        const double2* T = trin + tn1;
        B0 = T[0]; B1 = T[NF]; B2 = T[2 * NF];
        B3 = T[3 * NF]; B4 = T[4 * NF]; B5 = T[5 * NF];
      }
      if (tn1 + 64 < fend) bbB = bbn[tn1 + 64];
      // 3) survivors of round r: readlane-broadcast from A regs (no LDS)
      while (m) {
        int src = (int)__builtin_ctzll(m);
        m &= m - 1;
        int ti = tbase + src;
        double P = rl_d(A4.y, src);
        double Qq = rl_d(A5.x, src);
        double S = rl_d(A5.y, src);
        double uu = fma(px, P, Qq);
        if ((mf >> src) & 1ull) {
          // full-cover: no edge tests, zi only
          double py = py0;
#pragma unroll
          for (int rr = 0; rr < 4; ++rr) {
            double zi = fma(py, S, uu);
            if (zi > bz[rr]) { bz[rr] = zi; bi[rr] = ti; }
            py += 1.0;
          }
        } else {
          double EA0 = rl_d(A0.x, src), EB0 = rl_d(A0.y, src);
          double EC0 = rl_d(A1.x, src), EA1 = rl_d(A1.y, src);
          double EB1 = rl_d(A2.x, src), EC1 = rl_d(A2.y, src);
          double EA2 = rl_d(A3.x, src), EB2 = rl_d(A3.y, src);
          double EC2 = rl_d(A4.x, src);
          double q0 = fma(px, EA0, EC0);
          double q1 = fma(px, EA1, EC1);
          double q2 = fma(px, EA2, EC2);
          double py = py0;
#pragma unroll
          for (int rr = 0; rr < 4; ++rr) {
            double W0 = fma(py, EB0, q0);
            double W1 = fma(py, EB1, q1);
            double W2 = fma(py, EB2, q2);
            double zi = fma(py, S, uu);
            int msk = (__double2hiint(W0) | __double2hiint(W1) |
                       __double2hiint(W2)) >> 31;
            zi = __hiloint2double(__double2hiint(zi) | msk, __double2loint(zi));
            if (zi > bz[rr]) { bz[rr] = zi; bi[rr] = ti; }
            py += 1.0;
          }
        }
      }
      // 4) rotate double-buffer (SSA rename, no copies emitted)
      A0 = B0; A1 = B1; A2 = B2; A3 = B3; A4 = B4; A5 = B5;
      bbpA = bbpB;
    }

    // ---- endgame: 4-way merge through LDS ----
    __syncthreads();
#pragma unroll
    for (int r = 0; r < 4; ++r) {
      int pix = (yb + r) * 16 + xl;
      zbuf[w * 256 + pix] = bz[r];
      ibuf[w * 256 + pix] = bi[r];
    }
    __syncthreads();
    {
      int pix = tid;
      double z = zbuf[pix];
      int i = ibuf[pix];
#pragma unroll
      for (int qq = 1; qq < 4; ++qq) {
        double zq = zbuf[qq * 256 + pix];
        int iq = ibuf[qq * 256 + pix];
        bool take = (zq > z) || ((zq == z) && ((unsigned)iq < (unsigned)i));
        if (take) { z = zq; i = iq; }
      }
      int yloc = pix >> 4, xloc = pix & 15;
      int y = ytop + yloc;
      int xg = tx * 16 + xloc;
      int p = y * IMG_W + xg;
      size_t gid = (size_t)n * HW + p;
      out_idx[gid] = (float)i;

      // ---- fused interpolation + bilinear texture sample ----
      int idx = i;
      if (idx < 0) {
        for (int c = 0; c < 3; ++c) out_render[(size_t)(n * 3 + c) * HW + p] = 0.0f;
        out_mask[gid] = 0.0f;
        out_depth[gid] = 0.0f;
        out_vt[(size_t)gid * 2 + 0] = 0.0f;
        out_vt[(size_t)gid * 2 + 1] = 0.0f;
        for (int k = 0; k < 3; ++k) out_bary[(size_t)(n * 3 + k) * HW + p] = 0.0f;
      } else {
        int f0 = vi[idx * 3 + 0], f1 = vi[idx * 3 + 1], f2 = vi[idx * 3 + 2];
        int t0i = vti[idx * 3 + 0], t1i = vti[idx * 3 + 1], t2i = vti[idx * 3 + 2];
        const double* pv0 = vpixd + ((size_t)n * V + f0) * 3;
        const double* pv1 = vpixd + ((size_t)n * V + f1) * 3;
        const double* pv2 = vpixd + ((size_t)n * V + f2) * 3;
        float x0 = (float)pv0[0], y0 = (float)pv0[1], z0 = (float)pv0[2];
        float x1 = (float)pv1[0], y1 = (float)pv1[1], z1 = (float)pv1[2];
        float x2 = (float)pv2[0], y2 = (float)pv2[1], z2 = (float)pv2[2];
        float pxf = (float)xg, pyf = (float)y;
        float w0 = (pxf - x1) * (y2 - y1) - (pyf - y1) * (x2 - x1);
        float w1 = (pxf - x2) * (y0 - y2) - (pyf - y2) * (x0 - x2);
        float w2 = (pxf - x0) * (y1 - y0) - (pyf - y0) * (x1 - x0);
        float area = (x2 - x0) * (y1 - y0) - (y2 - y0) * (x1 - x0);
        float sa = (fabsf(area) > EPSF) ? area : 1.0f;
        float b0 = w0 / sa, b1 = w1 / sa, b2 = w2 / sa;
        float zz0 = fmaxf(z0, EPSF), zz1 = fmaxf(z1, EPSF), zz2 = fmaxf(z2, EPSF);
        float bz0 = b0 / zz0, bz1 = b1 / zz1, bz2 = b2 / zz2;
        float zi = fmaxf((bz0 + bz1) + bz2, EPSF);
        float r0 = bz0 / zi, r1 = bz1 / zi, r2 = bz2 / zi;
        float depth = 1.0f / zi;
        float u0 = vt[(size_t)t0i * 2 + 0], q0 = 1.0f - vt[(size_t)t0i * 2 + 1];
        float u1 = vt[(size_t)t1i * 2 + 0], q1 = 1.0f - vt[(size_t)t1i * 2 + 1];
        float u2 = vt[(size_t)t2i * 2 + 0], q2 = 1.0f - vt[(size_t)t2i * 2 + 1];
        float vtx = (r0 * u0 + r1 * u1) + r2 * u2;
        float vty = (r0 * q0 + r1 * q1) + r2 * q2;
        float gx = vtx * 2.0f - 1.0f;
        float gy = vty * 2.0f - 1.0f;
        float ix = ((gx + 1.0f) * 0.5f) * (float)TEX_W - 0.5f;
        float iy = ((gy + 1.0f) * 0.5f) * (float)TEX_H - 0.5f;
        float x0f = floorf(ix), y0f = floorf(iy);
        float fx = ix - x0f, fy = iy - y0f;
        int x0i = min(max((int)x0f, 0), TEX_W - 1);
        int x1i = min(max((int)x0f + 1, 0), TEX_W - 1);
        int y0i = min(max((int)y0f, 0), TEX_H - 1);
        int y1i = min(max((int)y0f + 1, 0), TEX_H - 1);
        float omfx = 1.0f - fx, omfy = 1.0f - fy;
        for (int c = 0; c < 3; ++c) {
          const float* tc = tex + (size_t)(n * 3 + c) * TEX_H * TEX_W;
          float v00 = tc[(size_t)y0i * TEX_W + x0i];
          float v01 = tc[(size_t)y0i * TEX_W + x1i];
          float v10 = tc[(size_t)y1i * TEX_W + x0i];
          float v11 = tc[(size_t)y1i * TEX_W + x1i];
          float o = (v00 * omfx + v01 * fx) * omfy + (v10 * omfx + v11 * fx) * fy;
          out_render[(size_t)(n * 3 + c) * HW + p] = o;
        }
        out_mask[gid] = 1.0f;
        out_depth[gid] = depth;
        out_vt[(size_t)gid * 2 + 0] = vtx;
        out_vt[(size_t)gid * 2 + 1] = vty;
        out_bary[(size_t)(n * 3 + 0) * HW + p] = r0;
        out_bary[(size_t)(n * 3 + 1) * HW + p] = r1;
        out_bary[(size_t)(n * 3 + 2) * HW + p] = r2;
      }
    }
  }
}

// ---------------------------------------------------------------------------
extern "C" void kernel_launch(void* const* d_in, const int* in_sizes, int n_in,
                              void* d_out, int out_size, void* d_ws, size_t ws_size,
                              hipStream_t stream) {
  const float* v = (const float*)d_in[0];
  const float* tex = (const float*)d_in[1];
  const float* vt = (const float*)d_in[2];
  const int* vi = (const int*)d_in[3];
  const int* vti = (const int*)d_in[4];
  const float* campos = (const float*)d_in[5];
  const float* camrot = (const float*)d_in[6];
  const float* focal = (const float*)d_in[7];
  const float* princpt = (const float*)d_in[8];
  int N = in_sizes[5] / 3;            // campos (N,3)
  int V = in_sizes[0] / (3 * N);      // v (N,V,3)
  int F = in_sizes[3] / 3;            // vi (F,3)

  char* wp = (char*)d_ws;
  double* vpixd = (double*)wp;
  wp += sizeof(double) * (size_t)N * V * 3;      // 196608 B
  double2* tri = (double2*)wp;
  wp += sizeof(double2) * (size_t)N * F * 6;     // 393216 B (6 SoA planes)
  float4* bbox = (float4*)wp;
  wp += sizeof(float4) * (size_t)N * F;          //  65536 B
  int* counter = (int*)wp;                       //      4 B

  int nv = N * V;
  k_project<<<(nv + 255) / 256, 256, 0, stream>>>(v, campos, camrot, focal,
                                                  princpt, vpixd, N, V);
  int nf = N * F;
  k_setup<<<(nf + 255) / 256, 256, 0, stream>>>(vpixd, vi, tri, bbox, counter,
                                                N, V, F);
  int nblk = 1024;                     // 4 blocks/CU resident
  int tot = N * TILES_PER_IMG;
  if (nblk > tot) nblk = tot;
  k_raster<<<nblk, 256, 0, stream>>>(tri, bbox, counter, vpixd, vt, vi, vti,
                                     tex, (float*)d_out, N, V, F);
}